// Round 9
// baseline (1257.504 us; speedup 1.0000x reference)
//
#include <hip/hip_runtime.h>
#include <hip/hip_bf16.h>
#include <cstdint>
#include <cstddef>

using bf16 = __hip_bfloat16;
typedef __bf16 bf16x8 __attribute__((ext_vector_type(8)));
typedef float f32x4 __attribute__((ext_vector_type(4)));

#define ATTN_SCALE 0.08838834764831845f  // 1/sqrt(128)

__device__ __forceinline__ void gload_lds16(const void* g, void* l) {
  __builtin_amdgcn_global_load_lds((__attribute__((address_space(1))) void*)g,
                                   (__attribute__((address_space(3))) void*)l,
                                   16, 0, 0);
}

// ---------------------------------------------------------------------------
// fp32 -> bf16 convert, 4 elements/thread (16B load, 8B store). n % 1024 == 0.
// ---------------------------------------------------------------------------
__global__ __launch_bounds__(256) void cvt_f32_to_bf16(
    const float* __restrict__ src, bf16* __restrict__ dst, int n) {
  const int i = (blockIdx.x * 256 + threadIdx.x) * 4;
  if (i >= n) return;
  const float4 v = *reinterpret_cast<const float4*>(src + i);
  bf16 tmp[4];
  tmp[0] = __float2bfloat16(v.x);
  tmp[1] = __float2bfloat16(v.y);
  tmp[2] = __float2bfloat16(v.z);
  tmp[3] = __float2bfloat16(v.w);
  *reinterpret_cast<ushort4*>(dst + i) = *reinterpret_cast<const ushort4*>(tmp);
}

// ---------------------------------------------------------------------------
// NT GEMM: C[M,N] = A[M,K] * B[N,K]^T (+ bias[N] fp32), bf16 in, fp32 acc.
// Output: bf16 to Cb if non-null, else fp32 to Cf.
// 128x128 tile, BK=32, 256 threads = 4 waves in 2x2 quadrants of 64x64.
// ---------------------------------------------------------------------------
__global__ __launch_bounds__(256) void gemm_nt(
    const bf16* __restrict__ A, const bf16* __restrict__ B,
    const float* __restrict__ bias, bf16* __restrict__ Cb,
    float* __restrict__ Cf, int M, int N, int K) {
  __shared__ bf16 As[128 * 32];
  __shared__ bf16 Bs[128 * 32];
  const int tid  = threadIdx.x;
  const int w    = tid >> 6, lane = tid & 63;
  const int wr   = w >> 1, wc = w & 1;
  const int g4   = lane >> 4, l16 = lane & 15;
  const int bm   = blockIdx.x * 128, bn = blockIdx.y * 128;

  f32x4 acc[4][4];
#pragma unroll
  for (int m = 0; m < 4; ++m)
#pragma unroll
    for (int n = 0; n < 4; ++n) acc[m][n] = (f32x4){0.f, 0.f, 0.f, 0.f};

  for (int k0 = 0; k0 < K; k0 += 32) {
    __syncthreads();  // prior-iter LDS reads done before restage
#pragma unroll
    for (int j = 0; j < 2; ++j) {
      const int c = j * 256 + w * 64 + lane;   // chunk id 0..511 (16B chunks)
      const int row = c >> 2, cc = (c & 3) * 8;
      gload_lds16(&A[(size_t)(bm + row) * K + k0 + cc],
                  &As[(size_t)(j * 256 + w * 64) * 8]);
      gload_lds16(&B[(size_t)(bn + row) * K + k0 + cc],
                  &Bs[(size_t)(j * 256 + w * 64) * 8]);
    }
    __syncthreads();  // staged data visible (vmcnt drained by barrier)

    bf16x8 af[4], bfrag[4];
#pragma unroll
    for (int m = 0; m < 4; ++m)
      af[m] = *reinterpret_cast<const bf16x8*>(
          &As[(wr * 64 + m * 16 + l16) * 32 + g4 * 8]);
#pragma unroll
    for (int n = 0; n < 4; ++n)
      bfrag[n] = *reinterpret_cast<const bf16x8*>(
          &Bs[(wc * 64 + n * 16 + l16) * 32 + g4 * 8]);
#pragma unroll
    for (int m = 0; m < 4; ++m)
#pragma unroll
      for (int n = 0; n < 4; ++n)
        acc[m][n] = __builtin_amdgcn_mfma_f32_16x16x32_bf16(
            af[m], bfrag[n], acc[m][n], 0, 0, 0);
  }

  // epilogue: C/D layout col = lane&15, row = (lane>>4)*4 + r
#pragma unroll
  for (int n = 0; n < 4; ++n) {
    const int col = bn + wc * 64 + n * 16 + l16;
    const float bv = bias ? bias[col] : 0.0f;
#pragma unroll
    for (int m = 0; m < 4; ++m) {
      const int row = bm + wr * 64 + m * 16 + g4 * 4;
#pragma unroll
      for (int r = 0; r < 4; ++r) {
        const float val = acc[m][n][r] + bv;
        if (Cb) Cb[(size_t)(row + r) * N + col] = __float2bfloat16(val);
        else    Cf[(size_t)(row + r) * N + col] = val;
      }
    }
  }
}

// ---------------------------------------------------------------------------
// RoPE in place on q [4096][16*128] and k [4096][2*128], fp32 cos/sin tables.
// One thread per (s, head, d<64) pair. cos[s,d] == cos[s,d+64].
// ---------------------------------------------------------------------------
__global__ __launch_bounds__(256) void rope_kernel(
    bf16* __restrict__ q, bf16* __restrict__ k,
    const float* __restrict__ cos_t, const float* __restrict__ sin_t) {
  const int idx = blockIdx.x * 256 + threadIdx.x;
  const int QP = 4096 * 16 * 64;
  bf16* buf;
  int s, d;
  if (idx < QP) {
    s = idx >> 10;
    const int r = idx & 1023;
    const int h = r >> 6;
    d = r & 63;
    buf = q + (size_t)s * 2048 + h * 128;
  } else {
    const int i2 = idx - QP;
    s = i2 >> 7;
    const int r = i2 & 127;
    const int h = r >> 6;
    d = r & 63;
    buf = k + (size_t)s * 256 + h * 128;
  }
  const float c  = cos_t[s * 128 + d];
  const float sn = sin_t[s * 128 + d];
  const float x1 = __bfloat162float(buf[d]);
  const float x2 = __bfloat162float(buf[d + 64]);
  buf[d]      = __float2bfloat16(x1 * c - x2 * sn);
  buf[d + 64] = __float2bfloat16(x2 * c + x1 * sn);
}

// ---------------------------------------------------------------------------
// Transpose v [4096][256] -> vt [256][4096] (LDS 64x64 tiles, coalesced W).
// ---------------------------------------------------------------------------
__global__ __launch_bounds__(256) void transpose_v(
    const bf16* __restrict__ in, bf16* __restrict__ out) {
  __shared__ bf16 tile[64][72];
  const int t = threadIdx.x;
  const int r0 = blockIdx.x * 64;  // s-tile
  const int c0 = blockIdx.y * 64;  // c-tile
#pragma unroll
  for (int j = 0; j < 2; ++j) {
    const int cn = j * 256 + t;
    const int row = cn >> 3, col = (cn & 7) * 8;
    *reinterpret_cast<bf16x8*>(&tile[row][col]) =
        *reinterpret_cast<const bf16x8*>(&in[(size_t)(r0 + row) * 256 + c0 + col]);
  }
  __syncthreads();
#pragma unroll
  for (int j = 0; j < 2; ++j) {
    const int cn = j * 256 + t;
    const int crow = cn >> 3, scol = (cn & 7) * 8;
    bf16 tmp[8];
#pragma unroll
    for (int e = 0; e < 8; ++e) tmp[e] = tile[scol + e][crow];
    *reinterpret_cast<bf16x8*>(&out[(size_t)(c0 + crow) * 4096 + r0 + scol]) =
        *reinterpret_cast<bf16x8*>(tmp);
  }
}

// ---------------------------------------------------------------------------
// Flash attention, causal, GQA 8:1. Grid (64 q-tiles reversed, 16 heads),
// 256 threads = 4 independent waves, each owns 16 q-rows. No __syncthreads.
// K and V^T fragments read straight from global (L2-resident, 4 MB total).
// P bounced through wave-private LDS to convert C-layout -> A-layout.
// ---------------------------------------------------------------------------
__global__ __launch_bounds__(256) void attn_kernel(
    const bf16* __restrict__ q, const bf16* __restrict__ k,
    const bf16* __restrict__ vt, bf16* __restrict__ o) {
  __shared__ bf16 Ps[4][16][72];
  const int tid = threadIdx.x, w = tid >> 6, lane = tid & 63;
  const int g4 = lane >> 4, l16 = lane & 15;
  const int qt = (int)gridDim.x - 1 - (int)blockIdx.x;  // heavy blocks first
  const int h  = blockIdx.y;
  const int g  = h >> 3;  // kv head
  const int qbase = qt * 64 + w * 16;

  // Q fragments: A[row=l16][kd = kc*32 + g4*8 + j]
  bf16x8 aq[4];
#pragma unroll
  for (int kc = 0; kc < 4; ++kc)
    aq[kc] = *reinterpret_cast<const bf16x8*>(
        &q[(size_t)(qbase + l16) * 2048 + h * 128 + kc * 32 + g4 * 8]);

  f32x4 acc_o[8];
#pragma unroll
  for (int no = 0; no < 8; ++no) acc_o[no] = (f32x4){0.f, 0.f, 0.f, 0.f};
  float m_r[4] = {-1e30f, -1e30f, -1e30f, -1e30f};
  float l_r[4] = {0.f, 0.f, 0.f, 0.f};

  for (int t = 0; t <= qt; ++t) {
    const int kb = t * 64;
    // ---- scores S = Q K^T : 16x64, fp32 ----
    f32x4 sc[4];
#pragma unroll
    for (int nt = 0; nt < 4; ++nt) sc[nt] = (f32x4){0.f, 0.f, 0.f, 0.f};
#pragma unroll
    for (int nt = 0; nt < 4; ++nt)
#pragma unroll
      for (int kc = 0; kc < 4; ++kc) {
        const bf16x8 bk = *reinterpret_cast<const bf16x8*>(
            &k[(size_t)(kb + nt * 16 + l16) * 256 + g * 128 + kc * 32 + g4 * 8]);
        sc[nt] = __builtin_amdgcn_mfma_f32_16x16x32_bf16(aq[kc], bk, sc[nt], 0, 0, 0);
      }
    // ---- scale + causal mask ----
#pragma unroll
    for (int nt = 0; nt < 4; ++nt)
#pragma unroll
      for (int r = 0; r < 4; ++r) {
        float s = sc[nt][r] * ATTN_SCALE;
        if (t == qt) {
          const int col = kb + nt * 16 + l16;
          const int row = qbase + g4 * 4 + r;
          if (col > row) s = -1e30f;
        }
        sc[nt][r] = s;
      }
    // ---- online softmax (row = (lane>>4)*4 + r, cols spread over 16 lanes) --
#pragma unroll
    for (int r = 0; r < 4; ++r) {
      float tmax = fmaxf(fmaxf(sc[0][r], sc[1][r]), fmaxf(sc[2][r], sc[3][r]));
      tmax = fmaxf(tmax, __shfl_xor(tmax, 1));
      tmax = fmaxf(tmax, __shfl_xor(tmax, 2));
      tmax = fmaxf(tmax, __shfl_xor(tmax, 4));
      tmax = fmaxf(tmax, __shfl_xor(tmax, 8));
      const float mn = fmaxf(m_r[r], tmax);
      const float alpha = __expf(m_r[r] - mn);
      m_r[r] = mn;
      float rsum = 0.f;
#pragma unroll
      for (int nt = 0; nt < 4; ++nt) {
        const float p = __expf(sc[nt][r] - mn);
        sc[nt][r] = p;
        rsum += p;
      }
      rsum += __shfl_xor(rsum, 1);
      rsum += __shfl_xor(rsum, 2);
      rsum += __shfl_xor(rsum, 4);
      rsum += __shfl_xor(rsum, 8);
      l_r[r] = l_r[r] * alpha + rsum;
#pragma unroll
      for (int no = 0; no < 8; ++no) acc_o[no][r] *= alpha;
    }
    // ---- P: C-layout regs -> LDS (bf16) -> A-layout frags ----
#pragma unroll
    for (int nt = 0; nt < 4; ++nt)
#pragma unroll
      for (int r = 0; r < 4; ++r)
        Ps[w][g4 * 4 + r][l16 + 16 * nt] = __float2bfloat16(sc[nt][r]);

    // safety fence: ensure wave's ds_writes complete before cross-lane ds_read
    asm volatile("s_waitcnt lgkmcnt(0)" ::: "memory");
    __builtin_amdgcn_sched_barrier(0);

    bf16x8 ap[2];
#pragma unroll
    for (int kc = 0; kc < 2; ++kc)
      ap[kc] = *reinterpret_cast<const bf16x8*>(&Ps[w][l16][kc * 32 + g4 * 8]);
    // ---- O += P V : B[kv][c] = vt[c][kb+kv], 8 contiguous kv per lane ----
#pragma unroll
    for (int no = 0; no < 8; ++no)
#pragma unroll
      for (int kc = 0; kc < 2; ++kc) {
        const bf16x8 bv = *reinterpret_cast<const bf16x8*>(
            &vt[(size_t)(g * 128 + no * 16 + l16) * 4096 + kb + kc * 32 + g4 * 8]);
        acc_o[no] = __builtin_amdgcn_mfma_f32_16x16x32_bf16(ap[kc], bv, acc_o[no], 0, 0, 0);
      }
  }

  // ---- normalize + store ----
#pragma unroll
  for (int r = 0; r < 4; ++r) {
    const float inv = 1.0f / l_r[r];
    const int row = qbase + g4 * 4 + r;
#pragma unroll
    for (int no = 0; no < 8; ++no)
      o[(size_t)row * 2048 + h * 128 + no * 16 + l16] =
          __float2bfloat16(acc_o[no][r] * inv);
  }
}

// ---------------------------------------------------------------------------
// Workspace layout (peak 46 MiB; buffers reused in stream order):
//   [0,16)   hsb (hidden bf16) ... later reused as at_ws (attn out)
//   [16,24)  wbuf (one weight bf16, reused for wq/wk/wv/wo)
//   [24,40)  q_ws   [40,42) k_ws   [42,44) v_ws   [44,46) vt_ws
// d_out is FP32 (reference output dtype) — final GEMM writes float.
// ---------------------------------------------------------------------------
extern "C" void kernel_launch(void* const* d_in, const int* in_sizes, int n_in,
                              void* d_out, int out_size, void* d_ws, size_t ws_size,
                              hipStream_t stream) {
  const float* hs    = (const float*)d_in[0];
  // d_in[1] = attention_mask (unused: causal mask computed analytically)
  const float* cosf_ = (const float*)d_in[2];
  const float* sinf_ = (const float*)d_in[3];
  const float* wq    = (const float*)d_in[4];
  const float* bq    = (const float*)d_in[5];
  const float* wk    = (const float*)d_in[6];
  const float* bk    = (const float*)d_in[7];
  const float* wv    = (const float*)d_in[8];
  const float* bv    = (const float*)d_in[9];
  const float* wo    = (const float*)d_in[10];
  float* out = (float*)d_out;

  char* ws = (char*)d_ws;
  const size_t MB = 1024 * 1024;
  bf16* hsb   = (bf16*)(ws);             // 16 MiB (4096x2048)
  bf16* wbuf  = (bf16*)(ws + 16 * MB);   //  8 MiB (up to 2048x2048)
  bf16* q_ws  = (bf16*)(ws + 24 * MB);   // 16 MiB
  bf16* k_ws  = (bf16*)(ws + 40 * MB);   //  2 MiB
  bf16* v_ws  = (bf16*)(ws + 42 * MB);   //  2 MiB
  bf16* vt_ws = (bf16*)(ws + 44 * MB);   //  2 MiB
  bf16* at_ws = (bf16*)(ws);             // reuse hsb region (dead after v GEMM)

  const dim3 blk(256);
  // hidden -> bf16
  cvt_f32_to_bf16<<<dim3(8192), blk, 0, stream>>>(hs, hsb, 4096 * 2048);
  // q projection
  cvt_f32_to_bf16<<<dim3(4096), blk, 0, stream>>>(wq, wbuf, 2048 * 2048);
  gemm_nt<<<dim3(32, 16), blk, 0, stream>>>(hsb, wbuf, bq, q_ws, nullptr,
                                            4096, 2048, 2048);
  // k projection
  cvt_f32_to_bf16<<<dim3(512), blk, 0, stream>>>(wk, wbuf, 256 * 2048);
  gemm_nt<<<dim3(32, 2), blk, 0, stream>>>(hsb, wbuf, bk, k_ws, nullptr,
                                           4096, 256, 2048);
  // v projection
  cvt_f32_to_bf16<<<dim3(512), blk, 0, stream>>>(wv, wbuf, 256 * 2048);
  gemm_nt<<<dim3(32, 2), blk, 0, stream>>>(hsb, wbuf, bv, v_ws, nullptr,
                                           4096, 256, 2048);
  // rope on q and k (4096*18*64 threads exactly)
  rope_kernel<<<dim3(18432), blk, 0, stream>>>(q_ws, k_ws, cosf_, sinf_);
  // v -> v^T
  transpose_v<<<dim3(64, 4), blk, 0, stream>>>(v_ws, vt_ws);
  // flash attention (writes at_ws over the dead hsb region)
  attn_kernel<<<dim3(64, 16), blk, 0, stream>>>(q_ws, k_ws, vt_ws, at_ws);
  // output projection -> FP32 d_out
  cvt_f32_to_bf16<<<dim3(4096), blk, 0, stream>>>(wo, wbuf, 2048 * 2048);
  gemm_nt<<<dim3(32, 16), blk, 0, stream>>>(at_ws, wbuf, nullptr, nullptr, out,
                                            4096, 2048, 2048);
}

// Round 10
// 697.033 us; speedup vs baseline: 1.8041x; 1.8041x over previous
//
#include <hip/hip_runtime.h>
#include <hip/hip_bf16.h>
#include <cstdint>
#include <cstddef>

using bf16 = __hip_bfloat16;
typedef __bf16 bf16x8 __attribute__((ext_vector_type(8)));
typedef float f32x4 __attribute__((ext_vector_type(4)));

#define ATTN_SCALE 0.08838834764831845f  // 1/sqrt(128)

__device__ __forceinline__ void gload_lds16(const void* g, void* l) {
  __builtin_amdgcn_global_load_lds((__attribute__((address_space(1))) void*)g,
                                   (__attribute__((address_space(3))) void*)l,
                                   16, 0, 0);
}

// ---------------------------------------------------------------------------
// fp32 -> bf16 convert, 4 elements/thread (16B load, 8B store). n % 1024 == 0.
// ---------------------------------------------------------------------------
__global__ __launch_bounds__(256) void cvt_f32_to_bf16(
    const float* __restrict__ src, bf16* __restrict__ dst, int n) {
  const int i = (blockIdx.x * 256 + threadIdx.x) * 4;
  if (i >= n) return;
  const float4 v = *reinterpret_cast<const float4*>(src + i);
  bf16 tmp[4];
  tmp[0] = __float2bfloat16(v.x);
  tmp[1] = __float2bfloat16(v.y);
  tmp[2] = __float2bfloat16(v.z);
  tmp[3] = __float2bfloat16(v.w);
  *reinterpret_cast<ushort4*>(dst + i) = *reinterpret_cast<const ushort4*>(tmp);
}

// ---------------------------------------------------------------------------
// NT GEMM: C[M,N] = A[M,K] * B[N,K]^T (+ bias[N] fp32), bf16 in, fp32 acc.
// Output: bf16 to Cb if non-null, else fp32 to Cf.
// 128x128 tile, BK=32, 256 threads = 4 waves in 2x2 quadrants of 64x64.
// ---------------------------------------------------------------------------
__global__ __launch_bounds__(256) void gemm_nt(
    const bf16* __restrict__ A, const bf16* __restrict__ B,
    const float* __restrict__ bias, bf16* __restrict__ Cb,
    float* __restrict__ Cf, int M, int N, int K) {
  __shared__ bf16 As[128 * 32];
  __shared__ bf16 Bs[128 * 32];
  const int tid  = threadIdx.x;
  const int w    = tid >> 6, lane = tid & 63;
  const int wr   = w >> 1, wc = w & 1;
  const int g4   = lane >> 4, l16 = lane & 15;
  const int bm   = blockIdx.x * 128, bn = blockIdx.y * 128;

  f32x4 acc[4][4];
#pragma unroll
  for (int m = 0; m < 4; ++m)
#pragma unroll
    for (int n = 0; n < 4; ++n) acc[m][n] = (f32x4){0.f, 0.f, 0.f, 0.f};

  for (int k0 = 0; k0 < K; k0 += 32) {
    __syncthreads();  // prior-iter LDS reads done before restage
#pragma unroll
    for (int j = 0; j < 2; ++j) {
      const int c = j * 256 + w * 64 + lane;   // chunk id 0..511 (16B chunks)
      const int row = c >> 2, cc = (c & 3) * 8;
      gload_lds16(&A[(size_t)(bm + row) * K + k0 + cc],
                  &As[(size_t)(j * 256 + w * 64) * 8]);
      gload_lds16(&B[(size_t)(bn + row) * K + k0 + cc],
                  &Bs[(size_t)(j * 256 + w * 64) * 8]);
    }
    __syncthreads();  // staged data visible (vmcnt drained by barrier)

    bf16x8 af[4], bfrag[4];
#pragma unroll
    for (int m = 0; m < 4; ++m)
      af[m] = *reinterpret_cast<const bf16x8*>(
          &As[(wr * 64 + m * 16 + l16) * 32 + g4 * 8]);
#pragma unroll
    for (int n = 0; n < 4; ++n)
      bfrag[n] = *reinterpret_cast<const bf16x8*>(
          &Bs[(wc * 64 + n * 16 + l16) * 32 + g4 * 8]);
#pragma unroll
    for (int m = 0; m < 4; ++m)
#pragma unroll
      for (int n = 0; n < 4; ++n)
        acc[m][n] = __builtin_amdgcn_mfma_f32_16x16x32_bf16(
            af[m], bfrag[n], acc[m][n], 0, 0, 0);
  }

  // epilogue: C/D layout col = lane&15, row = (lane>>4)*4 + r
#pragma unroll
  for (int n = 0; n < 4; ++n) {
    const int col = bn + wc * 64 + n * 16 + l16;
    const float bv = bias ? bias[col] : 0.0f;
#pragma unroll
    for (int m = 0; m < 4; ++m) {
      const int row = bm + wr * 64 + m * 16 + g4 * 4;
#pragma unroll
      for (int r = 0; r < 4; ++r) {
        const float val = acc[m][n][r] + bv;
        if (Cb) Cb[(size_t)(row + r) * N + col] = __float2bfloat16(val);
        else    Cf[(size_t)(row + r) * N + col] = val;
      }
    }
  }
}

// ---------------------------------------------------------------------------
// RoPE in place on q [4096][16*128] and k [4096][2*128], fp32 cos/sin tables.
// One thread per (s, head, d<64) pair. cos[s,d] == cos[s,d+64].
// ---------------------------------------------------------------------------
__global__ __launch_bounds__(256) void rope_kernel(
    bf16* __restrict__ q, bf16* __restrict__ k,
    const float* __restrict__ cos_t, const float* __restrict__ sin_t) {
  const int idx = blockIdx.x * 256 + threadIdx.x;
  const int QP = 4096 * 16 * 64;
  bf16* buf;
  int s, d;
  if (idx < QP) {
    s = idx >> 10;
    const int r = idx & 1023;
    const int h = r >> 6;
    d = r & 63;
    buf = q + (size_t)s * 2048 + h * 128;
  } else {
    const int i2 = idx - QP;
    s = i2 >> 7;
    const int r = i2 & 127;
    const int h = r >> 6;
    d = r & 63;
    buf = k + (size_t)s * 256 + h * 128;
  }
  const float c  = cos_t[s * 128 + d];
  const float sn = sin_t[s * 128 + d];
  const float x1 = __bfloat162float(buf[d]);
  const float x2 = __bfloat162float(buf[d + 64]);
  buf[d]      = __float2bfloat16(x1 * c - x2 * sn);
  buf[d + 64] = __float2bfloat16(x2 * c + x1 * sn);
}

// ---------------------------------------------------------------------------
// Transpose v [4096][256] -> vt [256][4096] (LDS 64x64 tiles, coalesced W).
// ---------------------------------------------------------------------------
__global__ __launch_bounds__(256) void transpose_v(
    const bf16* __restrict__ in, bf16* __restrict__ out) {
  __shared__ bf16 tile[64][72];
  const int t = threadIdx.x;
  const int r0 = blockIdx.x * 64;  // s-tile
  const int c0 = blockIdx.y * 64;  // c-tile
#pragma unroll
  for (int j = 0; j < 2; ++j) {
    const int cn = j * 256 + t;
    const int row = cn >> 3, col = (cn & 7) * 8;
    *reinterpret_cast<bf16x8*>(&tile[row][col]) =
        *reinterpret_cast<const bf16x8*>(&in[(size_t)(r0 + row) * 256 + c0 + col]);
  }
  __syncthreads();
#pragma unroll
  for (int j = 0; j < 2; ++j) {
    const int cn = j * 256 + t;
    const int crow = cn >> 3, scol = (cn & 7) * 8;
    bf16 tmp[8];
#pragma unroll
    for (int e = 0; e < 8; ++e) tmp[e] = tile[scol + e][crow];
    *reinterpret_cast<bf16x8*>(&out[(size_t)(c0 + crow) * 4096 + r0 + scol]) =
        *reinterpret_cast<bf16x8*>(tmp);
  }
}

// ---------------------------------------------------------------------------
// Flash attention, causal, GQA 8:1. Grid (64 q-tiles reversed, 16 heads),
// 256 threads = 4 waves, each owns 16 q-rows of a 64-row q-tile.
// Per kv-tile: K (64x128) and V^T (128x64) are cooperatively staged into LDS
// via global_load_lds (XOR-swizzled source, linear dest; reads re-apply the
// swizzle) and shared by all 4 waves. 2 barriers/iteration.
// ---------------------------------------------------------------------------
__global__ __launch_bounds__(256) void attn_kernel(
    const bf16* __restrict__ q, const bf16* __restrict__ k,
    const bf16* __restrict__ vt, bf16* __restrict__ o) {
  __shared__ bf16 Ks[64 * 128];   // 16 KiB, row stride 256B, swizzled
  __shared__ bf16 Vs[128 * 64];   // 16 KiB, row stride 128B, swizzled
  __shared__ bf16 Ps[4][16][72];  // per-wave P bounce
  const int tid = threadIdx.x, w = tid >> 6, lane = tid & 63;
  const int g4 = lane >> 4, l16 = lane & 15;
  const int sw = (l16 & 7) << 4;  // read-side XOR swizzle (row&7)<<4
  const int qt = (int)gridDim.x - 1 - (int)blockIdx.x;  // heavy blocks first
  const int h  = blockIdx.y;
  const int g  = h >> 3;  // kv head
  const int qbase = qt * 64 + w * 16;

  // Q fragments: A[row=l16][kd = kc*32 + g4*8 + j]
  bf16x8 aq[4];
#pragma unroll
  for (int kc = 0; kc < 4; ++kc)
    aq[kc] = *reinterpret_cast<const bf16x8*>(
        &q[(size_t)(qbase + l16) * 2048 + h * 128 + kc * 32 + g4 * 8]);

  f32x4 acc_o[8];
#pragma unroll
  for (int no = 0; no < 8; ++no) acc_o[no] = (f32x4){0.f, 0.f, 0.f, 0.f};
  float m_r[4] = {-1e30f, -1e30f, -1e30f, -1e30f};
  float l_r[4] = {0.f, 0.f, 0.f, 0.f};

  for (int t = 0; t <= qt; ++t) {
    const int kb = t * 64;
    // ---- stage K tile (64 rows x 256B) + V^T tile (128 rows x 128B) ----
    __syncthreads();  // prior-iter LDS reads done before overwrite
#pragma unroll
    for (int p = 0; p < 4; ++p) {
      // K: chunk c in [0,1024), row r = c/16, in-row byte cb = (c%16)*16.
      const int ck = p * 256 + tid;
      const int rk = ck >> 4;
      const int cbk = ((ck & 15) * 16) ^ ((rk & 7) << 4);  // inverse-swz src
      gload_lds16(&k[(size_t)(kb + rk) * 256 + g * 128 + (cbk >> 1)],
                  &Ks[(size_t)(p * 256 + w * 64) * 8]);
      // V: chunk c in [0,1024), row dr = c/8, in-row byte cb = (c%8)*16.
      const int cv = p * 256 + tid;
      const int dr = cv >> 3;
      const int cbv = ((cv & 7) * 16) ^ ((dr & 7) << 4);
      gload_lds16(&vt[(size_t)(g * 128 + dr) * 4096 + kb + (cbv >> 1)],
                  &Vs[(size_t)(p * 256 + w * 64) * 8]);
    }
    __syncthreads();  // staged data visible

    // ---- scores S = Q K^T : 16x64, fp32 (K from LDS, swizzled read) ----
    f32x4 sc[4];
#pragma unroll
    for (int nt = 0; nt < 4; ++nt) sc[nt] = (f32x4){0.f, 0.f, 0.f, 0.f};
#pragma unroll
    for (int nt = 0; nt < 4; ++nt)
#pragma unroll
      for (int kc = 0; kc < 4; ++kc) {
        const int rk = nt * 16 + l16;  // rk&7 == l16&7
        const bf16x8 bk = *reinterpret_cast<const bf16x8*>(
            &Ks[rk * 128 + (((kc * 64 + g4 * 16) ^ sw) >> 1)]);
        sc[nt] = __builtin_amdgcn_mfma_f32_16x16x32_bf16(aq[kc], bk, sc[nt], 0, 0, 0);
      }
    // ---- scale + causal mask ----
#pragma unroll
    for (int nt = 0; nt < 4; ++nt)
#pragma unroll
      for (int r = 0; r < 4; ++r) {
        float s = sc[nt][r] * ATTN_SCALE;
        if (t == qt) {
          const int col = kb + nt * 16 + l16;
          const int row = qbase + g4 * 4 + r;
          if (col > row) s = -1e30f;
        }
        sc[nt][r] = s;
      }
    // ---- online softmax (row = (lane>>4)*4 + r, cols spread over 16 lanes) --
#pragma unroll
    for (int r = 0; r < 4; ++r) {
      float tmax = fmaxf(fmaxf(sc[0][r], sc[1][r]), fmaxf(sc[2][r], sc[3][r]));
      tmax = fmaxf(tmax, __shfl_xor(tmax, 1));
      tmax = fmaxf(tmax, __shfl_xor(tmax, 2));
      tmax = fmaxf(tmax, __shfl_xor(tmax, 4));
      tmax = fmaxf(tmax, __shfl_xor(tmax, 8));
      const float mn = fmaxf(m_r[r], tmax);
      const float alpha = __expf(m_r[r] - mn);
      m_r[r] = mn;
      float rsum = 0.f;
#pragma unroll
      for (int nt = 0; nt < 4; ++nt) {
        const float p = __expf(sc[nt][r] - mn);
        sc[nt][r] = p;
        rsum += p;
      }
      rsum += __shfl_xor(rsum, 1);
      rsum += __shfl_xor(rsum, 2);
      rsum += __shfl_xor(rsum, 4);
      rsum += __shfl_xor(rsum, 8);
      l_r[r] = l_r[r] * alpha + rsum;
#pragma unroll
      for (int no = 0; no < 8; ++no) acc_o[no][r] *= alpha;
    }
    // ---- P: C-layout regs -> LDS (bf16) -> A-layout frags ----
#pragma unroll
    for (int nt = 0; nt < 4; ++nt)
#pragma unroll
      for (int r = 0; r < 4; ++r)
        Ps[w][g4 * 4 + r][l16 + 16 * nt] = __float2bfloat16(sc[nt][r]);

    // safety fence: ensure wave's ds_writes complete before cross-lane ds_read
    asm volatile("s_waitcnt lgkmcnt(0)" ::: "memory");
    __builtin_amdgcn_sched_barrier(0);

    bf16x8 ap[2];
#pragma unroll
    for (int kc = 0; kc < 2; ++kc)
      ap[kc] = *reinterpret_cast<const bf16x8*>(&Ps[w][l16][kc * 32 + g4 * 8]);
    // ---- O += P V : V^T from LDS (swizzled read), 8 contiguous kv/lane ----
#pragma unroll
    for (int no = 0; no < 8; ++no)
#pragma unroll
      for (int kc = 0; kc < 2; ++kc) {
        const int dr = no * 16 + l16;  // dr&7 == l16&7
        const bf16x8 bv = *reinterpret_cast<const bf16x8*>(
            &Vs[dr * 64 + (((kc * 64 + g4 * 16) ^ sw) >> 1)]);
        acc_o[no] = __builtin_amdgcn_mfma_f32_16x16x32_bf16(ap[kc], bv, acc_o[no], 0, 0, 0);
      }
  }

  // ---- normalize + store ----
#pragma unroll
  for (int r = 0; r < 4; ++r) {
    const float inv = 1.0f / l_r[r];
    const int row = qbase + g4 * 4 + r;
#pragma unroll
    for (int no = 0; no < 8; ++no)
      o[(size_t)row * 2048 + h * 128 + no * 16 + l16] =
          __float2bfloat16(acc_o[no][r] * inv);
  }
}

// ---------------------------------------------------------------------------
// Workspace layout (peak 46 MiB; buffers reused in stream order):
//   [0,16)   hsb (hidden bf16) ... later reused as at_ws (attn out)
//   [16,24)  wbuf (one weight bf16, reused for wq/wk/wv/wo)
//   [24,40)  q_ws   [40,42) k_ws   [42,44) v_ws   [44,46) vt_ws
// d_out is FP32 (reference output dtype) — final GEMM writes float.
// ---------------------------------------------------------------------------
extern "C" void kernel_launch(void* const* d_in, const int* in_sizes, int n_in,
                              void* d_out, int out_size, void* d_ws, size_t ws_size,
                              hipStream_t stream) {
  const float* hs    = (const float*)d_in[0];
  // d_in[1] = attention_mask (unused: causal mask computed analytically)
  const float* cosf_ = (const float*)d_in[2];
  const float* sinf_ = (const float*)d_in[3];
  const float* wq    = (const float*)d_in[4];
  const float* bq    = (const float*)d_in[5];
  const float* wk    = (const float*)d_in[6];
  const float* bk    = (const float*)d_in[7];
  const float* wv    = (const float*)d_in[8];
  const float* bv    = (const float*)d_in[9];
  const float* wo    = (const float*)d_in[10];
  float* out = (float*)d_out;

  char* ws = (char*)d_ws;
  const size_t MB = 1024 * 1024;
  bf16* hsb   = (bf16*)(ws);             // 16 MiB (4096x2048)
  bf16* wbuf  = (bf16*)(ws + 16 * MB);   //  8 MiB (up to 2048x2048)
  bf16* q_ws  = (bf16*)(ws + 24 * MB);   // 16 MiB
  bf16* k_ws  = (bf16*)(ws + 40 * MB);   //  2 MiB
  bf16* v_ws  = (bf16*)(ws + 42 * MB);   //  2 MiB
  bf16* vt_ws = (bf16*)(ws + 44 * MB);   //  2 MiB
  bf16* at_ws = (bf16*)(ws);             // reuse hsb region (dead after v GEMM)

  const dim3 blk(256);
  // hidden -> bf16
  cvt_f32_to_bf16<<<dim3(8192), blk, 0, stream>>>(hs, hsb, 4096 * 2048);
  // q projection
  cvt_f32_to_bf16<<<dim3(4096), blk, 0, stream>>>(wq, wbuf, 2048 * 2048);
  gemm_nt<<<dim3(32, 16), blk, 0, stream>>>(hsb, wbuf, bq, q_ws, nullptr,
                                            4096, 2048, 2048);
  // k projection
  cvt_f32_to_bf16<<<dim3(512), blk, 0, stream>>>(wk, wbuf, 256 * 2048);
  gemm_nt<<<dim3(32, 2), blk, 0, stream>>>(hsb, wbuf, bk, k_ws, nullptr,
                                           4096, 256, 2048);
  // v projection
  cvt_f32_to_bf16<<<dim3(512), blk, 0, stream>>>(wv, wbuf, 256 * 2048);
  gemm_nt<<<dim3(32, 2), blk, 0, stream>>>(hsb, wbuf, bv, v_ws, nullptr,
                                           4096, 256, 2048);
  // rope on q and k (4096*18*64 threads exactly)
  rope_kernel<<<dim3(18432), blk, 0, stream>>>(q_ws, k_ws, cosf_, sinf_);
  // v -> v^T
  transpose_v<<<dim3(64, 4), blk, 0, stream>>>(v_ws, vt_ws);
  // flash attention (writes at_ws over the dead hsb region)
  attn_kernel<<<dim3(64, 16), blk, 0, stream>>>(q_ws, k_ws, vt_ws, at_ws);
  // output projection -> FP32 d_out
  cvt_f32_to_bf16<<<dim3(4096), blk, 0, stream>>>(wo, wbuf, 2048 * 2048);
  gemm_nt<<<dim3(32, 16), blk, 0, stream>>>(at_ws, wbuf, nullptr, nullptr, out,
                                            4096, 2048, 2048);
}

// Round 11
// 688.568 us; speedup vs baseline: 1.8263x; 1.0123x over previous
//
#include <hip/hip_runtime.h>
#include <hip/hip_bf16.h>
#include <cstdint>
#include <cstddef>

using bf16 = __hip_bfloat16;
typedef __bf16 bf16x8 __attribute__((ext_vector_type(8)));
typedef float f32x4 __attribute__((ext_vector_type(4)));

#define ATTN_SCALE 0.08838834764831845f            // 1/sqrt(128)
#define ATTN_SCALE_LOG2E 0.1275216096914508f       // 1/sqrt(128) * log2(e)

__device__ __forceinline__ void gload_lds16(const void* g, void* l) {
  __builtin_amdgcn_global_load_lds((__attribute__((address_space(1))) void*)g,
                                   (__attribute__((address_space(3))) void*)l,
                                   16, 0, 0);
}

__device__ __forceinline__ float exp2_fast(float x) {
  float r;
  asm("v_exp_f32 %0, %1" : "=v"(r) : "v"(x));
  return r;
}

// ---------------------------------------------------------------------------
// fp32 -> bf16 convert, 4 elements/thread (16B load, 8B store). n % 1024 == 0.
// ---------------------------------------------------------------------------
__global__ __launch_bounds__(256) void cvt_f32_to_bf16(
    const float* __restrict__ src, bf16* __restrict__ dst, int n) {
  const int i = (blockIdx.x * 256 + threadIdx.x) * 4;
  if (i >= n) return;
  const float4 v = *reinterpret_cast<const float4*>(src + i);
  bf16 tmp[4];
  tmp[0] = __float2bfloat16(v.x);
  tmp[1] = __float2bfloat16(v.y);
  tmp[2] = __float2bfloat16(v.z);
  tmp[3] = __float2bfloat16(v.w);
  *reinterpret_cast<ushort4*>(dst + i) = *reinterpret_cast<const ushort4*>(tmp);
}

// ---------------------------------------------------------------------------
// NT GEMM: C[M,N] = A[M,K] * B[N,K]^T (+ bias[N] fp32), bf16 in, fp32 acc.
// Output: bf16 to Cb if non-null, else fp32 to Cf.
// 128x128 tile, BK=32, 256 threads = 4 waves in 2x2 quadrants of 64x64.
// ---------------------------------------------------------------------------
__global__ __launch_bounds__(256) void gemm_nt(
    const bf16* __restrict__ A, const bf16* __restrict__ B,
    const float* __restrict__ bias, bf16* __restrict__ Cb,
    float* __restrict__ Cf, int M, int N, int K) {
  __shared__ bf16 As[128 * 32];
  __shared__ bf16 Bs[128 * 32];
  const int tid  = threadIdx.x;
  const int w    = tid >> 6, lane = tid & 63;
  const int wr   = w >> 1, wc = w & 1;
  const int g4   = lane >> 4, l16 = lane & 15;
  const int bm   = blockIdx.x * 128, bn = blockIdx.y * 128;

  f32x4 acc[4][4];
#pragma unroll
  for (int m = 0; m < 4; ++m)
#pragma unroll
    for (int n = 0; n < 4; ++n) acc[m][n] = (f32x4){0.f, 0.f, 0.f, 0.f};

  for (int k0 = 0; k0 < K; k0 += 32) {
    __syncthreads();  // prior-iter LDS reads done before restage
#pragma unroll
    for (int j = 0; j < 2; ++j) {
      const int c = j * 256 + w * 64 + lane;   // chunk id 0..511 (16B chunks)
      const int row = c >> 2, cc = (c & 3) * 8;
      gload_lds16(&A[(size_t)(bm + row) * K + k0 + cc],
                  &As[(size_t)(j * 256 + w * 64) * 8]);
      gload_lds16(&B[(size_t)(bn + row) * K + k0 + cc],
                  &Bs[(size_t)(j * 256 + w * 64) * 8]);
    }
    __syncthreads();  // staged data visible (vmcnt drained by barrier)

    bf16x8 af[4], bfrag[4];
#pragma unroll
    for (int m = 0; m < 4; ++m)
      af[m] = *reinterpret_cast<const bf16x8*>(
          &As[(wr * 64 + m * 16 + l16) * 32 + g4 * 8]);
#pragma unroll
    for (int n = 0; n < 4; ++n)
      bfrag[n] = *reinterpret_cast<const bf16x8*>(
          &Bs[(wc * 64 + n * 16 + l16) * 32 + g4 * 8]);
#pragma unroll
    for (int m = 0; m < 4; ++m)
#pragma unroll
      for (int n = 0; n < 4; ++n)
        acc[m][n] = __builtin_amdgcn_mfma_f32_16x16x32_bf16(
            af[m], bfrag[n], acc[m][n], 0, 0, 0);
  }

  // epilogue: C/D layout col = lane&15, row = (lane>>4)*4 + r
#pragma unroll
  for (int n = 0; n < 4; ++n) {
    const int col = bn + wc * 64 + n * 16 + l16;
    const float bv = bias ? bias[col] : 0.0f;
#pragma unroll
    for (int m = 0; m < 4; ++m) {
      const int row = bm + wr * 64 + m * 16 + g4 * 4;
#pragma unroll
      for (int r = 0; r < 4; ++r) {
        const float val = acc[m][n][r] + bv;
        if (Cb) Cb[(size_t)(row + r) * N + col] = __float2bfloat16(val);
        else    Cf[(size_t)(row + r) * N + col] = val;
      }
    }
  }
}

// ---------------------------------------------------------------------------
// RoPE in place on q [4096][16*128] and k [4096][2*128], fp32 cos/sin tables.
// One thread per (s, head, d<64) pair. cos[s,d] == cos[s,d+64].
// ---------------------------------------------------------------------------
__global__ __launch_bounds__(256) void rope_kernel(
    bf16* __restrict__ q, bf16* __restrict__ k,
    const float* __restrict__ cos_t, const float* __restrict__ sin_t) {
  const int idx = blockIdx.x * 256 + threadIdx.x;
  const int QP = 4096 * 16 * 64;
  bf16* buf;
  int s, d;
  if (idx < QP) {
    s = idx >> 10;
    const int r = idx & 1023;
    const int h = r >> 6;
    d = r & 63;
    buf = q + (size_t)s * 2048 + h * 128;
  } else {
    const int i2 = idx - QP;
    s = i2 >> 7;
    const int r = i2 & 127;
    const int h = r >> 6;
    d = r & 63;
    buf = k + (size_t)s * 256 + h * 128;
  }
  const float c  = cos_t[s * 128 + d];
  const float sn = sin_t[s * 128 + d];
  const float x1 = __bfloat162float(buf[d]);
  const float x2 = __bfloat162float(buf[d + 64]);
  buf[d]      = __float2bfloat16(x1 * c - x2 * sn);
  buf[d + 64] = __float2bfloat16(x2 * c + x1 * sn);
}

// ---------------------------------------------------------------------------
// Transpose v [4096][256] -> vt [256][4096] (LDS 64x64 tiles, coalesced W).
// ---------------------------------------------------------------------------
__global__ __launch_bounds__(256) void transpose_v(
    const bf16* __restrict__ in, bf16* __restrict__ out) {
  __shared__ bf16 tile[64][72];
  const int t = threadIdx.x;
  const int r0 = blockIdx.x * 64;  // s-tile
  const int c0 = blockIdx.y * 64;  // c-tile
#pragma unroll
  for (int j = 0; j < 2; ++j) {
    const int cn = j * 256 + t;
    const int row = cn >> 3, col = (cn & 7) * 8;
    *reinterpret_cast<bf16x8*>(&tile[row][col]) =
        *reinterpret_cast<const bf16x8*>(&in[(size_t)(r0 + row) * 256 + c0 + col]);
  }
  __syncthreads();
#pragma unroll
  for (int j = 0; j < 2; ++j) {
    const int cn = j * 256 + t;
    const int crow = cn >> 3, scol = (cn & 7) * 8;
    bf16 tmp[8];
#pragma unroll
    for (int e = 0; e < 8; ++e) tmp[e] = tile[scol + e][crow];
    *reinterpret_cast<bf16x8*>(&out[(size_t)(c0 + crow) * 4096 + r0 + scol]) =
        *reinterpret_cast<bf16x8*>(tmp);
  }
}

// ---------------------------------------------------------------------------
// Flash attention, causal, GQA 8:1. Grid (64 q-tiles reversed, 16 heads),
// 256 threads = 4 waves, each owns 16 q-rows of a 64-row q-tile.
// 2-phase pipeline: K/V tiles double-buffered in LDS; stage of tile t+1 is
// issued BEFORE computing tile t; ONE barrier per iteration (its implicit
// vmcnt(0) drains the prefetch under the compute). XOR-swizzled (source-side)
// staging; reads re-apply the swizzle. Softmax in exp2 domain with
// wave-uniform rescale skip.
// ---------------------------------------------------------------------------
__global__ __launch_bounds__(256) void attn_kernel(
    const bf16* __restrict__ q, const bf16* __restrict__ k,
    const bf16* __restrict__ vt, bf16* __restrict__ o) {
  __shared__ bf16 Ks[2][64 * 128];   // 2 x 16 KiB, row stride 256B, swizzled
  __shared__ bf16 Vs[2][128 * 64];   // 2 x 16 KiB, row stride 128B, swizzled
  __shared__ bf16 Ps[4][16][72];     // per-wave P bounce
  const int tid = threadIdx.x, w = tid >> 6, lane = tid & 63;
  const int g4 = lane >> 4, l16 = lane & 15;
  const int sw = (l16 & 7) << 4;  // read-side XOR swizzle (row&7)<<4
  const int qt = (int)gridDim.x - 1 - (int)blockIdx.x;  // heavy blocks first
  const int h  = blockIdx.y;
  const int g  = h >> 3;  // kv head
  const int qbase = qt * 64 + w * 16;

#define STAGE_KV(buf, kb_)                                                    \
  {                                                                           \
    _Pragma("unroll")                                                         \
    for (int p = 0; p < 4; ++p) {                                             \
      const int ck = p * 256 + tid;                                           \
      const int rk = ck >> 4;                                                 \
      const int cbk = ((ck & 15) * 16) ^ ((rk & 7) << 4);                     \
      gload_lds16(&k[(size_t)((kb_) + rk) * 256 + g * 128 + (cbk >> 1)],      \
                  &Ks[buf][(size_t)(p * 256 + w * 64) * 8]);                  \
      const int dr = ck >> 3;                                                 \
      const int cbv = ((ck & 7) * 16) ^ ((dr & 7) << 4);                      \
      gload_lds16(&vt[(size_t)(g * 128 + dr) * 4096 + (kb_) + (cbv >> 1)],    \
                  &Vs[buf][(size_t)(p * 256 + w * 64) * 8]);                  \
    }                                                                         \
  }

  // Q fragments: A[row=l16][kd = kc*32 + g4*8 + j]
  bf16x8 aq[4];
#pragma unroll
  for (int kc = 0; kc < 4; ++kc)
    aq[kc] = *reinterpret_cast<const bf16x8*>(
        &q[(size_t)(qbase + l16) * 2048 + h * 128 + kc * 32 + g4 * 8]);

  f32x4 acc_o[8];
#pragma unroll
  for (int no = 0; no < 8; ++no) acc_o[no] = (f32x4){0.f, 0.f, 0.f, 0.f};
  float m_r[4] = {-1e30f, -1e30f, -1e30f, -1e30f};
  float l_r[4] = {0.f, 0.f, 0.f, 0.f};

  int cur = 0;
  STAGE_KV(0, 0);
  __syncthreads();  // tile 0 staged (implicit vmcnt(0))

  for (int t = 0; t <= qt; ++t) {
    const int kb = t * 64;
    // ---- prefetch next tile into the other buffer (no wait) ----
    if (t < qt) STAGE_KV(cur ^ 1, kb + 64);

    const bf16* Kc = Ks[cur];
    const bf16* Vc = Vs[cur];

    // ---- scores S = Q K^T : 16x64, exp2-domain scale (K from LDS) ----
    f32x4 sc[4];
#pragma unroll
    for (int nt = 0; nt < 4; ++nt) sc[nt] = (f32x4){0.f, 0.f, 0.f, 0.f};
#pragma unroll
    for (int nt = 0; nt < 4; ++nt)
#pragma unroll
      for (int kc = 0; kc < 4; ++kc) {
        const int rk = nt * 16 + l16;  // rk&7 == l16&7
        const bf16x8 bk = *reinterpret_cast<const bf16x8*>(
            &Kc[rk * 128 + (((kc * 64 + g4 * 16) ^ sw) >> 1)]);
        sc[nt] = __builtin_amdgcn_mfma_f32_16x16x32_bf16(aq[kc], bk, sc[nt], 0, 0, 0);
      }
    // ---- scale (into log2 units) + causal mask ----
#pragma unroll
    for (int nt = 0; nt < 4; ++nt)
#pragma unroll
      for (int r = 0; r < 4; ++r) {
        float s = sc[nt][r] * ATTN_SCALE_LOG2E;
        if (t == qt) {
          const int col = kb + nt * 16 + l16;
          const int row = qbase + g4 * 4 + r;
          if (col > row) s = -1e30f;
        }
        sc[nt][r] = s;
      }
    // ---- online softmax, exp2 domain ----
    float mn[4];
    bool up = false;
#pragma unroll
    for (int r = 0; r < 4; ++r) {
      float tmax = fmaxf(fmaxf(sc[0][r], sc[1][r]), fmaxf(sc[2][r], sc[3][r]));
      tmax = fmaxf(tmax, __shfl_xor(tmax, 1));
      tmax = fmaxf(tmax, __shfl_xor(tmax, 2));
      tmax = fmaxf(tmax, __shfl_xor(tmax, 4));
      tmax = fmaxf(tmax, __shfl_xor(tmax, 8));
      mn[r] = fmaxf(m_r[r], tmax);
      up = up || (mn[r] > m_r[r]);
    }
    if (__any(up)) {  // wave-uniform rescale (alpha==1 exactly when skipped)
#pragma unroll
      for (int r = 0; r < 4; ++r) {
        const float alpha = exp2_fast(m_r[r] - mn[r]);
        m_r[r] = mn[r];
        l_r[r] *= alpha;
#pragma unroll
        for (int no = 0; no < 8; ++no) acc_o[no][r] *= alpha;
      }
    }
#pragma unroll
    for (int r = 0; r < 4; ++r) {
      float rsum = 0.f;
#pragma unroll
      for (int nt = 0; nt < 4; ++nt) {
        const float p = exp2_fast(sc[nt][r] - m_r[r]);
        sc[nt][r] = p;
        rsum += p;
      }
      rsum += __shfl_xor(rsum, 1);
      rsum += __shfl_xor(rsum, 2);
      rsum += __shfl_xor(rsum, 4);
      rsum += __shfl_xor(rsum, 8);
      l_r[r] += rsum;
    }
    // ---- P: C-layout regs -> LDS (bf16) -> A-layout frags ----
#pragma unroll
    for (int nt = 0; nt < 4; ++nt)
#pragma unroll
      for (int r = 0; r < 4; ++r)
        Ps[w][g4 * 4 + r][l16 + 16 * nt] = __float2bfloat16(sc[nt][r]);

    // wave-internal fence: ds_writes complete before cross-lane ds_read
    asm volatile("s_waitcnt lgkmcnt(0)" ::: "memory");
    __builtin_amdgcn_sched_barrier(0);

    bf16x8 ap[2];
#pragma unroll
    for (int kc = 0; kc < 2; ++kc)
      ap[kc] = *reinterpret_cast<const bf16x8*>(&Ps[w][l16][kc * 32 + g4 * 8]);
    // ---- O += P V : V^T from LDS (swizzled read), 8 contiguous kv/lane ----
#pragma unroll
    for (int no = 0; no < 8; ++no)
#pragma unroll
      for (int kc = 0; kc < 2; ++kc) {
        const int dr = no * 16 + l16;  // dr&7 == l16&7
        const bf16x8 bv = *reinterpret_cast<const bf16x8*>(
            &Vc[dr * 64 + (((kc * 64 + g4 * 16) ^ sw) >> 1)]);
        acc_o[no] = __builtin_amdgcn_mfma_f32_16x16x32_bf16(ap[kc], bv, acc_o[no], 0, 0, 0);
      }

    // one barrier/iter: drains next-tile prefetch (vmcnt 0) AND closes reads
    __syncthreads();
    cur ^= 1;
  }
#undef STAGE_KV

  // ---- normalize + store ----
#pragma unroll
  for (int r = 0; r < 4; ++r) {
    const float inv = 1.0f / l_r[r];
    const int row = qbase + g4 * 4 + r;
#pragma unroll
    for (int no = 0; no < 8; ++no)
      o[(size_t)row * 2048 + h * 128 + no * 16 + l16] =
          __float2bfloat16(acc_o[no][r] * inv);
  }
}

// ---------------------------------------------------------------------------
// Workspace layout (peak 46 MiB; buffers reused in stream order):
//   [0,16)   hsb (hidden bf16) ... later reused as at_ws (attn out)
//   [16,24)  wbuf (one weight bf16, reused for wq/wk/wv/wo)
//   [24,40)  q_ws   [40,42) k_ws   [42,44) v_ws   [44,46) vt_ws
// d_out is FP32 (reference output dtype) — final GEMM writes float.
// ---------------------------------------------------------------------------
extern "C" void kernel_launch(void* const* d_in, const int* in_sizes, int n_in,
                              void* d_out, int out_size, void* d_ws, size_t ws_size,
                              hipStream_t stream) {
  const float* hs    = (const float*)d_in[0];
  // d_in[1] = attention_mask (unused: causal mask computed analytically)
  const float* cosf_ = (const float*)d_in[2];
  const float* sinf_ = (const float*)d_in[3];
  const float* wq    = (const float*)d_in[4];
  const float* bq    = (const float*)d_in[5];
  const float* wk    = (const float*)d_in[6];
  const float* bk    = (const float*)d_in[7];
  const float* wv    = (const float*)d_in[8];
  const float* bv    = (const float*)d_in[9];
  const float* wo    = (const float*)d_in[10];
  float* out = (float*)d_out;

  char* ws = (char*)d_ws;
  const size_t MB = 1024 * 1024;
  bf16* hsb   = (bf16*)(ws);             // 16 MiB (4096x2048)
  bf16* wbuf  = (bf16*)(ws + 16 * MB);   //  8 MiB (up to 2048x2048)
  bf16* q_ws  = (bf16*)(ws + 24 * MB);   // 16 MiB
  bf16* k_ws  = (bf16*)(ws + 40 * MB);   //  2 MiB
  bf16* v_ws  = (bf16*)(ws + 42 * MB);   //  2 MiB
  bf16* vt_ws = (bf16*)(ws + 44 * MB);   //  2 MiB
  bf16* at_ws = (bf16*)(ws);             // reuse hsb region (dead after v GEMM)

  const dim3 blk(256);
  // hidden -> bf16
  cvt_f32_to_bf16<<<dim3(8192), blk, 0, stream>>>(hs, hsb, 4096 * 2048);
  // q projection
  cvt_f32_to_bf16<<<dim3(4096), blk, 0, stream>>>(wq, wbuf, 2048 * 2048);
  gemm_nt<<<dim3(32, 16), blk, 0, stream>>>(hsb, wbuf, bq, q_ws, nullptr,
                                            4096, 2048, 2048);
  // k projection
  cvt_f32_to_bf16<<<dim3(512), blk, 0, stream>>>(wk, wbuf, 256 * 2048);
  gemm_nt<<<dim3(32, 2), blk, 0, stream>>>(hsb, wbuf, bk, k_ws, nullptr,
                                           4096, 256, 2048);
  // v projection
  cvt_f32_to_bf16<<<dim3(512), blk, 0, stream>>>(wv, wbuf, 256 * 2048);
  gemm_nt<<<dim3(32, 2), blk, 0, stream>>>(hsb, wbuf, bv, v_ws, nullptr,
                                           4096, 256, 2048);
  // rope on q and k (4096*18*64 threads exactly)
  rope_kernel<<<dim3(18432), blk, 0, stream>>>(q_ws, k_ws, cosf_, sinf_);
  // v -> v^T
  transpose_v<<<dim3(64, 4), blk, 0, stream>>>(v_ws, vt_ws);
  // flash attention (writes at_ws over the dead hsb region)
  attn_kernel<<<dim3(64, 16), blk, 0, stream>>>(q_ws, k_ws, vt_ws, at_ws);
  // output projection -> FP32 d_out
  cvt_f32_to_bf16<<<dim3(4096), blk, 0, stream>>>(wo, wbuf, 2048 * 2048);
  gemm_nt<<<dim3(32, 16), blk, 0, stream>>>(at_ws, wbuf, nullptr, nullptr, out,
                                            4096, 2048, 2048);
}